// Round 7
// baseline (380.452 us; speedup 1.0000x reference)
//
#include <hip/hip_runtime.h>

typedef short short8 __attribute__((ext_vector_type(8)));
typedef float f32x16 __attribute__((ext_vector_type(16)));
typedef unsigned int uint;

#define C_IN  128
#define H_IN  112
#define W_IN  112
#define K_OUT 256
#define H_OUTD 110
#define W_OUTD 110
#define NBATCH 32

// xT layout: [n][h][w][cpos(128)] bf16, cpos = (c&64) | ((c&63) ^ ((w&7)<<3))
#define XT_ELEMS (NBATCH*H_IN*W_IN*128)    // 51,380,224
// F2 layout: [S(36 = rs*4+cstep)][wm(4)][mf(2)][ksub(2)][lane(64)][e(8)]
//   k_out = wm*64 + mf*32 + (lane&31) ; c = cstep*32 + ksub*16 + (lane>>5)*8 + e
#define F_ELEMS  (36*4*2*2*64*8)           // 294,912

__device__ __forceinline__ unsigned short f2bf(float f) {
  uint u = __float_as_uint(f);
  u += 0x7fffu + ((u >> 16) & 1u);   // RNE
  return (unsigned short)(u >> 16);
}

__device__ __forceinline__ void gll16(const unsigned short* g, unsigned short* l) {
  __builtin_amdgcn_global_load_lds(
      (const __attribute__((address_space(1))) void*)g,
      (__attribute__((address_space(3))) void*)(uint)(uintptr_t)l, 16, 0, 0);
}

// ---------------- prep: x (NCHW f32) -> xT (swizzled bf16) ----------------
__global__ __launch_bounds__(256) void xpose_kernel(const float* __restrict__ x,
                                                    unsigned short* __restrict__ xT) {
  __shared__ unsigned short sm[H_IN * 128];   // [w][cpos] 28,672 B
  const int n = blockIdx.y;
  const int h = blockIdx.x;
  const int tid = threadIdx.x;
  for (int it = 0; it < 28; ++it) {
    int idx = it*256 + tid;            // 0..7167  (64 c-pairs x 112 w)
    int w  = idx % 112;
    int cp = idx / 112;                // 0..63
    int c0 = cp*2;
    const float* px = x + ((size_t)(n*C_IN + c0)*H_IN + h)*W_IN + w;
    float f0 = px[0];
    float f1 = px[H_IN*W_IN];
    uint key  = ((uint)w & 7u) << 3;
    uint cpos = ((uint)c0 & 64u) | (((uint)c0 & 63u) ^ key);
    uint v = (uint)f2bf(f0) | ((uint)f2bf(f1) << 16);
    *(uint*)&sm[w*128 + cpos] = v;
  }
  __syncthreads();
  for (int it = 0; it < 7; ++it) {
    int idx = it*256 + tid;            // 0..1791 chunks of 8 shorts
    int w  = idx >> 4;
    int cc = idx & 15;
    uint4 v = *(const uint4*)&sm[w*128 + cc*8];
    size_t off = (((size_t)n*H_IN + h)*W_IN + w)*128 + cc*8;
    *(uint4*)&xT[off] = v;
  }
}

// ---- prep: filt (OIHW f32) -> F2 fragment-packed bf16 for 32x32x16 ----
__global__ __launch_bounds__(256) void fprep_kernel(const float* __restrict__ ft,
                                                    unsigned short* __restrict__ F) {
  int idx = blockIdx.x*256 + threadIdx.x;   // < 294912
  int e    = idx & 7;
  int lane = (idx >> 3) & 63;
  int ksub = (idx >> 9) & 1;
  int mf   = (idx >> 10) & 1;
  int wm   = (idx >> 11) & 3;
  int S    = idx >> 13;                     // 0..35
  int rs   = S >> 2;
  int cstep= S & 3;
  int k = wm*64 + mf*32 + (lane & 31);
  int c = cstep*32 + ksub*16 + (lane >> 5)*8 + e;
  F[idx] = f2bf(ft[(k*C_IN + c)*9 + rs]);
}

// ---------------- main implicit-GEMM conv ----------------
// block: 512 thr (8 waves, 4M x 2N), tile = 256 K_out x (8h x 16w)
// wave tile 64k x 64px via 2x2 mfma_f32_32x32x16_bf16 frags (8 MFMA/step)
// smX: full 128-c halo 10x18x128 bf16 = 46,080 B, staged ONCE; barrier-free K-loop
// A: fragment-packed F (L2-resident), global->reg depth-1 named double buffer
__global__ __launch_bounds__(512, 4) void conv_gemm(const unsigned short* __restrict__ xT,
                                                    const unsigned short* __restrict__ F,
                                                    float* __restrict__ out) {
  __shared__ unsigned short smX[10*18*128];   // 46,080 B
  // bijective XCD swizzle: 3136 blocks = 8 XCDs x 392
  const int bid  = blockIdx.y*98 + blockIdx.x;
  const int wgid = (bid & 7)*392 + (bid >> 3);
  const int tile = wgid % 98;                 // 14 h-tiles x 7 w-tiles
  const int n    = wgid / 98;
  const int tid  = threadIdx.x;
  const int lane = tid & 63;
  const int wid  = tid >> 6;
  const int wm   = wid & 3;                   // M quadrant (64 k each)
  const int wn   = wid >> 2;                  // N half (4 h-rows each)
  const int l15  = lane & 15;
  const int lh1  = (lane >> 4) & 1;
  const int lh5  = lane >> 5;
  const int th   = tile / 7;
  const int tw   = tile - th*7;
  const int h0   = th*8;
  const int w0   = tw*16;

  // B cell bases: px col = lane&31 -> (hh = wn*4 + nf*2 + lh1, ww = l15)
  int cellb[2];
  #pragma unroll
  for (int nf = 0; nf < 2; ++nf)
    cellb[nf] = ((wn*4 + nf*2 + lh1)*18 + l15)*128;
  const int cbase = lh5*8;                    // lane part of B/A k-mapping

  f32x16 acc[2][2];
  #pragma unroll
  for (int mf = 0; mf < 2; ++mf)
    #pragma unroll
    for (int nf = 0; nf < 2; ++nf)
      #pragma unroll
      for (int e = 0; e < 16; ++e)
        acc[mf][nf][e] = 0.f;

  // per-wave A base; slice stride 8192 shorts; a[mf*2+ksub]
  const unsigned short* Aw = F + wm*2048 + lane*8;
  short8 aA[4], aB[4];
  #pragma unroll
  for (int u = 0; u < 4; ++u)
    aA[u] = *(const short8*)(Aw + u*512);

  // stage x halo (2880 x 16B chunks), async direct-to-LDS
  {
    const unsigned short* xbase = xT + (size_t)n*H_IN*W_IN*128;
    #pragma unroll
    for (int k = 0; k < 6; ++k) {
      int ci = k*512 + tid;
      if (ci < 2880) {
        int cell = ci >> 4, sub = ci & 15;
        int hh = cell / 18, ww = cell - hh*18;
        int hc = h0 + hh; if (hc > 111) hc = 111;
        int wc = w0 + ww; if (wc > 111) wc = 111;
        gll16(xbase + ((size_t)(hc*W_IN + wc))*128 + sub*8, &smX[ci*8]);
      }
    }
  }
  __syncthreads();   // only barrier (drains gll16 queue)

#define COMPUTE(J, AREG)                                                        \
  {                                                                             \
    const int rs = (J) >> 2, cstep = (J) & 3;                                   \
    const int r = rs/3, s = rs - r*3;                                           \
    const int key  = ((l15 + s) & 7) << 3;                                      \
    const int coff = (r*18 + s)*128;                                            \
    __builtin_amdgcn_s_setprio(1);                                              \
    _Pragma("unroll")                                                           \
    for (int ks = 0; ks < 2; ++ks) {                                            \
      const int cb   = cstep*32 + ks*16 + cbase;                                \
      const int cpos = (cb & 64) | ((cb & 63) ^ key);                           \
      _Pragma("unroll")                                                         \
      for (int nf = 0; nf < 2; ++nf) {                                          \
        short8 b = *(const short8*)&smX[cellb[nf] + coff + cpos];               \
        acc[0][nf] = __builtin_amdgcn_mfma_f32_32x32x16_bf16(AREG[ks],   b, acc[0][nf], 0, 0, 0); \
        acc[1][nf] = __builtin_amdgcn_mfma_f32_32x32x16_bf16(AREG[2+ks], b, acc[1][nf], 0, 0, 0); \
      }                                                                         \
    }                                                                           \
    __builtin_amdgcn_s_setprio(0);                                              \
  }

  for (int i = 0; i < 36; i += 2) {
    {
      const unsigned short* As = Aw + (size_t)(i + 1)*8192;
      #pragma unroll
      for (int u = 0; u < 4; ++u)
        aB[u] = *(const short8*)(As + u*512);
    }
    COMPUTE(i, aA);
    if (i + 2 < 36) {
      const unsigned short* As = Aw + (size_t)(i + 2)*8192;
      #pragma unroll
      for (int u = 0; u < 4; ++u)
        aA[u] = *(const short8*)(As + u*512);
    }
    COMPUTE(i + 1, aB);
  }
#undef COMPUTE

  // epilogue: D: col(px)=lane&31, row = (reg&3)+8*(reg>>2)+4*lh5
  const int wv = w0 + l15;
  #pragma unroll
  for (int nf = 0; nf < 2; ++nf) {
    const int hv = h0 + wn*4 + nf*2 + lh1;
    if (hv < H_OUTD && wv < W_OUTD) {
      float* po = out + (size_t)n*K_OUT*(H_OUTD*W_OUTD) + hv*W_OUTD + wv;
      #pragma unroll
      for (int mf = 0; mf < 2; ++mf) {
        #pragma unroll
        for (int reg = 0; reg < 16; ++reg) {
          int krow = (reg & 3) + 8*(reg >> 2) + 4*lh5;
          int k = wm*64 + mf*32 + krow;
          po[(size_t)k*(H_OUTD*W_OUTD)] = acc[mf][nf][reg];
        }
      }
    }
  }
}

// ---------------- fallback (ws too small): naive fp32 ----------------
__global__ void naive_conv(const float* __restrict__ x, const float* __restrict__ ft,
                           float* __restrict__ out) {
  int idx = blockIdx.x*256 + threadIdx.x;
  int total = NBATCH*K_OUT*H_OUTD*W_OUTD;
  if (idx >= total) return;
  int w = idx % W_OUTD; int t = idx / W_OUTD;
  int h = t % H_OUTD; t /= H_OUTD;
  int k = t % K_OUT; int nn = t / K_OUT;
  float acc = 0.f;
  for (int c = 0; c < C_IN; ++c)
    for (int r = 0; r < 3; ++r)
      for (int s = 0; s < 3; ++s)
        acc += x[((size_t)(nn*C_IN + c)*H_IN + h + r)*W_IN + w + s]
             * ft[((k*C_IN + c)*3 + r)*3 + s];
  out[idx] = acc;
}

extern "C" void kernel_launch(void* const* d_in, const int* in_sizes, int n_in,
                              void* d_out, int out_size, void* d_ws, size_t ws_size,
                              hipStream_t stream) {
  (void)in_sizes; (void)n_in; (void)out_size;
  const float* x  = (const float*)d_in[0];
  const float* ft = (const float*)d_in[1];
  float* out = (float*)d_out;
  size_t need = (size_t)(XT_ELEMS + F_ELEMS) * sizeof(unsigned short);
  if (ws_size >= need) {
    unsigned short* xT = (unsigned short*)d_ws;
    unsigned short* F  = xT + XT_ELEMS;
    xpose_kernel<<<dim3(112, 32), 256, 0, stream>>>(x, xT);
    fprep_kernel<<<dim3(1152), 256, 0, stream>>>(ft, F);
    conv_gemm<<<dim3(98, 32), 512, 0, stream>>>(xT, F, out);
  } else {
    int total = NBATCH*K_OUT*H_OUTD*W_OUTD;
    naive_conv<<<(total + 255)/256, 256, 0, stream>>>(x, ft, out);
  }
}

// Round 8
// 348.645 us; speedup vs baseline: 1.0912x; 1.0912x over previous
//
#include <hip/hip_runtime.h>

typedef short short8 __attribute__((ext_vector_type(8)));
typedef float f32x4 __attribute__((ext_vector_type(4)));
typedef unsigned int uint;

#define C_IN  128
#define H_IN  112
#define W_IN  112
#define K_OUT 256
#define H_OUTD 110
#define W_OUTD 110
#define NBATCH 32

// xT layout: [n][h][w][cpos(128)] bf16, cpos = (c&64) | ((c&63) ^ ((w&7)<<3))
#define XT_ELEMS (NBATCH*H_IN*W_IN*128)    // 51,380,224
// F2 layout: [S(36 = rs*4+cstep)][wm(4)][mt(4)][lane(64)][e(8)]
//   k = wm*64+mt*16+(lane&15) ; c = cstep*32 + (lane>>4)*8 + e
#define F_ELEMS  (36*4*4*64*8)             // 294,912

__device__ __forceinline__ unsigned short f2bf(float f) {
  uint u = __float_as_uint(f);
  u += 0x7fffu + ((u >> 16) & 1u);   // RNE
  return (unsigned short)(u >> 16);
}

__device__ __forceinline__ void gll16(const unsigned short* g, unsigned short* l) {
  __builtin_amdgcn_global_load_lds(
      (const __attribute__((address_space(1))) void*)g,
      (__attribute__((address_space(3))) void*)(uint)(uintptr_t)l, 16, 0, 0);
}

// ---------------- prep: x (NCHW f32) -> xT (swizzled bf16) ----------------
__global__ __launch_bounds__(256) void xpose_kernel(const float* __restrict__ x,
                                                    unsigned short* __restrict__ xT) {
  __shared__ unsigned short sm[H_IN * 128];   // [w][cpos] 28,672 B
  const int n = blockIdx.y;
  const int h = blockIdx.x;
  const int tid = threadIdx.x;
  for (int it = 0; it < 28; ++it) {
    int idx = it*256 + tid;            // 0..7167  (64 c-pairs x 112 w)
    int w  = idx % 112;
    int cp = idx / 112;                // 0..63
    int c0 = cp*2;
    const float* px = x + ((size_t)(n*C_IN + c0)*H_IN + h)*W_IN + w;
    float f0 = px[0];
    float f1 = px[H_IN*W_IN];
    uint key  = ((uint)w & 7u) << 3;
    uint cpos = ((uint)c0 & 64u) | (((uint)c0 & 63u) ^ key);
    uint v = (uint)f2bf(f0) | ((uint)f2bf(f1) << 16);
    *(uint*)&sm[w*128 + cpos] = v;
  }
  __syncthreads();
  for (int it = 0; it < 7; ++it) {
    int idx = it*256 + tid;            // 0..1791 chunks of 8 shorts
    int w  = idx >> 4;
    int cc = idx & 15;
    uint4 v = *(const uint4*)&sm[w*128 + cc*8];
    size_t off = (((size_t)n*H_IN + h)*W_IN + w)*128 + cc*8;
    *(uint4*)&xT[off] = v;
  }
}

// ---- prep: filt (OIHW f32) -> F2 fragment-packed bf16 (16x16 frags) ----
__global__ __launch_bounds__(256) void fprep_kernel(const float* __restrict__ ft,
                                                    unsigned short* __restrict__ F) {
  int idx = blockIdx.x*256 + threadIdx.x;   // < 294912
  int e    = idx & 7;
  int lane = (idx >> 3) & 63;
  int mt   = (idx >> 9) & 3;
  int wm   = (idx >> 11) & 3;
  int S    = idx >> 13;                     // 0..35
  int rs   = S >> 2;
  int cstep= S & 3;
  int k = wm*64 + mt*16 + (lane & 15);
  int c = cstep*32 + (lane >> 4)*8 + e;
  F[idx] = f2bf(ft[(k*C_IN + c)*9 + rs]);
}

// ---------------- main implicit-GEMM conv ----------------
// block: 512 thr (8 waves, 4M x 2N), output tile = 256 K_out x (16h x 16w)
// wave = 64k x 128px (4 mt x 8 nt of 16x16x32 frags), acc = 128 VGPR
// smX halo 18x18, stored [ph(2)][cell(324)][64] bf16 = 82,944 B, staged ONCE.
// Barrier-free K-loop; A: fragment-packed F, global->reg depth-1 dbuf.
__global__ __launch_bounds__(512, 2) void conv_gemm(const unsigned short* __restrict__ xT,
                                                    const unsigned short* __restrict__ F,
                                                    float* __restrict__ out) {
  __shared__ unsigned short smX[2*324*64];    // 82,944 B
  // bijective XCD swizzle: 1568 blocks = 8 XCDs x 196
  const int bid  = blockIdx.y*49 + blockIdx.x;
  const int wgid = (bid & 7)*196 + (bid >> 3);
  const int tile = wgid % 49;                 // 7 h-tiles x 7 w-tiles
  const int n    = wgid / 49;
  const int tid  = threadIdx.x;
  const int lane = tid & 63;
  const int wid  = tid >> 6;
  const int wm   = wid & 3;                   // M quadrant (64 k each)
  const int wn   = wid >> 2;                  // N half (8 h-rows each)
  const int l15  = lane & 15;
  const int lhi  = lane >> 4;                 // 0..3
  const int th   = tile / 7;
  const int tw   = tile - th*7;
  const int h0   = th*16;
  const int w0   = tw*16;

  int browb[8];
  #pragma unroll
  for (int nt = 0; nt < 8; ++nt)
    browb[nt] = ((wn*8 + nt)*18 + l15)*64;    // halo cell * 64 shorts

  f32x4 acc[4][8];
  #pragma unroll
  for (int mt = 0; mt < 4; ++mt)
    #pragma unroll
    for (int nt = 0; nt < 8; ++nt)
      acc[mt][nt] = (f32x4){0.f, 0.f, 0.f, 0.f};

  // per-wave A base; slice stride 8192 shorts
  const unsigned short* Aw = F + wm*2048 + lane*8;
  short8 aA[4], aB[4];
  #pragma unroll
  for (int u = 0; u < 4; ++u)
    aA[u] = *(const short8*)(Aw + u*512);

  // stage halo: 5184 chunks of 16B -> smX[ph][cell][64], linear LDS dest
  {
    const unsigned short* xbase = xT + (size_t)n*H_IN*W_IN*128;
    #pragma unroll
    for (int k = 0; k < 11; ++k) {
      int ci = k*512 + tid;
      if (ci < 5184) {
        int ph  = ci >= 2592;
        int rem = ci - ph*2592;
        int cell = rem >> 3, sub = rem & 7;
        int hh = cell / 18, ww = cell - hh*18;
        int hc = h0 + hh; if (hc > 111) hc = 111;
        int wc = w0 + ww; if (wc > 111) wc = 111;
        gll16(xbase + ((size_t)(hc*W_IN + wc))*128 + ph*64 + sub*8, &smX[ci*8]);
      }
    }
  }
  __syncthreads();   // only barrier (drains gll16 queue)

#define COMPUTE(J, AREG)                                                         \
  {                                                                              \
    const int rs = (J) >> 2, cstep = (J) & 3;                                    \
    const int r = rs/3, s = rs - r*3;                                            \
    const int key  = ((l15 + s) & 7) << 3;                                       \
    const int cb63 = (cstep & 1)*32 + lhi*8;                                     \
    const int off  = (cstep >> 1)*20736 + (r*18 + s)*64 + (cb63 ^ key);          \
    __builtin_amdgcn_s_setprio(1);                                               \
    _Pragma("unroll")                                                            \
    for (int nt = 0; nt < 8; ++nt) {                                             \
      short8 b = *(const short8*)&smX[browb[nt] + off];                          \
      _Pragma("unroll")                                                          \
      for (int mt = 0; mt < 4; ++mt)                                             \
        acc[mt][nt] = __builtin_amdgcn_mfma_f32_16x16x32_bf16(AREG[mt], b, acc[mt][nt], 0, 0, 0); \
    }                                                                            \
    __builtin_amdgcn_s_setprio(0);                                               \
  }

  for (int i = 0; i < 36; i += 2) {
    {
      const unsigned short* As = Aw + (size_t)(i + 1)*8192;
      #pragma unroll
      for (int u = 0; u < 4; ++u)
        aB[u] = *(const short8*)(As + u*512);
    }
    COMPUTE(i, aA);
    if (i + 2 < 36) {
      const unsigned short* As = Aw + (size_t)(i + 2)*8192;
      #pragma unroll
      for (int u = 0; u < 4; ++u)
        aA[u] = *(const short8*)(As + u*512);
    }
    COMPUTE(i + 1, aB);
  }
#undef COMPUTE

  // epilogue: D frag: col(px)=l15, row(k)=lhi*4+reg
  const int wv = w0 + l15;
  #pragma unroll
  for (int nt = 0; nt < 8; ++nt) {
    int hv = h0 + wn*8 + nt;
    if (hv < H_OUTD && wv < W_OUTD) {
      float* po = out + (size_t)n*K_OUT*(H_OUTD*W_OUTD) + hv*W_OUTD + wv;
      #pragma unroll
      for (int mt = 0; mt < 4; ++mt) {
        #pragma unroll
        for (int reg = 0; reg < 4; ++reg) {
          int k = wm*64 + mt*16 + lhi*4 + reg;
          po[(size_t)k*(H_OUTD*W_OUTD)] = acc[mt][nt][reg];
        }
      }
    }
  }
}

// ---------------- fallback (ws too small): naive fp32 ----------------
__global__ void naive_conv(const float* __restrict__ x, const float* __restrict__ ft,
                           float* __restrict__ out) {
  int idx = blockIdx.x*256 + threadIdx.x;
  int total = NBATCH*K_OUT*H_OUTD*W_OUTD;
  if (idx >= total) return;
  int w = idx % W_OUTD; int t = idx / W_OUTD;
  int h = t % H_OUTD; t /= H_OUTD;
  int k = t % K_OUT; int nn = t / K_OUT;
  float acc = 0.f;
  for (int c = 0; c < C_IN; ++c)
    for (int r = 0; r < 3; ++r)
      for (int s = 0; s < 3; ++s)
        acc += x[((size_t)(nn*C_IN + c)*H_IN + h + r)*W_IN + w + s]
             * ft[((k*C_IN + c)*3 + r)*3 + s];
  out[idx] = acc;
}

extern "C" void kernel_launch(void* const* d_in, const int* in_sizes, int n_in,
                              void* d_out, int out_size, void* d_ws, size_t ws_size,
                              hipStream_t stream) {
  (void)in_sizes; (void)n_in; (void)out_size;
  const float* x  = (const float*)d_in[0];
  const float* ft = (const float*)d_in[1];
  float* out = (float*)d_out;
  size_t need = (size_t)(XT_ELEMS + F_ELEMS) * sizeof(unsigned short);
  if (ws_size >= need) {
    unsigned short* xT = (unsigned short*)d_ws;
    unsigned short* F  = xT + XT_ELEMS;
    xpose_kernel<<<dim3(112, 32), 256, 0, stream>>>(x, xT);
    fprep_kernel<<<dim3(1152), 256, 0, stream>>>(ft, F);
    conv_gemm<<<dim3(49, 32), 512, 0, stream>>>(xT, F, out);
  } else {
    int total = NBATCH*K_OUT*H_OUTD*W_OUTD;
    naive_conv<<<(total + 255)/256, 256, 0, stream>>>(x, ft, out);
  }
}

// Round 9
// 343.656 us; speedup vs baseline: 1.1071x; 1.0145x over previous
//
#include <hip/hip_runtime.h>

typedef short short8 __attribute__((ext_vector_type(8)));
typedef float f32x4 __attribute__((ext_vector_type(4)));
typedef unsigned int uint;

#define C_IN  128
#define H_IN  112
#define W_IN  112
#define K_OUT 256
#define H_OUTD 110
#define W_OUTD 110
#define NBATCH 32

// xT layout: [n][h][w][cpos(128)] bf16, cpos = (c&64) | ((c&63) ^ ((w&7)<<3))
#define XT_ELEMS (NBATCH*H_IN*W_IN*128)    // 51,380,224
// F2 layout: [S(36)][wm(4)][mt(4)][lane(64)][e(8)], S = ph*18 + rs*2 + ch2
//   k = wm*64+mt*16+(lane&15) ; c = ph*64 + ch2*32 + (lane>>4)*8 + e
#define F_ELEMS  (36*4*4*64*8)             // 294,912

__device__ __forceinline__ unsigned short f2bf(float f) {
  uint u = __float_as_uint(f);
  u += 0x7fffu + ((u >> 16) & 1u);   // RNE
  return (unsigned short)(u >> 16);
}

__device__ __forceinline__ void gll16(const unsigned short* g, unsigned short* l) {
  __builtin_amdgcn_global_load_lds(
      (const __attribute__((address_space(1))) void*)g,
      (__attribute__((address_space(3))) void*)(uint)(uintptr_t)l, 16, 0, 0);
}

// ---------------- prep: x (NCHW f32) -> xT (swizzled bf16) ----------------
__global__ __launch_bounds__(256) void xpose_kernel(const float* __restrict__ x,
                                                    unsigned short* __restrict__ xT) {
  __shared__ unsigned short sm[H_IN * 128];   // [w][cpos] 28,672 B
  const int n = blockIdx.y;
  const int h = blockIdx.x;
  const int tid = threadIdx.x;
  for (int it = 0; it < 28; ++it) {
    int idx = it*256 + tid;            // 0..7167  (64 c-pairs x 112 w)
    int w  = idx % 112;
    int cp = idx / 112;                // 0..63
    int c0 = cp*2;
    const float* px = x + ((size_t)(n*C_IN + c0)*H_IN + h)*W_IN + w;
    float f0 = px[0];
    float f1 = px[H_IN*W_IN];
    uint key  = ((uint)w & 7u) << 3;
    uint cpos = ((uint)c0 & 64u) | (((uint)c0 & 63u) ^ key);
    uint v = (uint)f2bf(f0) | ((uint)f2bf(f1) << 16);
    *(uint*)&sm[w*128 + cpos] = v;
  }
  __syncthreads();
  for (int it = 0; it < 7; ++it) {
    int idx = it*256 + tid;            // 0..1791 chunks of 8 shorts
    int w  = idx >> 4;
    int cc = idx & 15;
    uint4 v = *(const uint4*)&sm[w*128 + cc*8];
    size_t off = (((size_t)n*H_IN + h)*W_IN + w)*128 + cc*8;
    *(uint4*)&xT[off] = v;
  }
}

// ---- prep: filt (OIHW f32) -> F2 fragment-packed bf16 (ph-major slices) ----
__global__ __launch_bounds__(256) void fprep_kernel(const float* __restrict__ ft,
                                                    unsigned short* __restrict__ F) {
  int idx = blockIdx.x*256 + threadIdx.x;   // < 294912
  int e    = idx & 7;
  int lane = (idx >> 3) & 63;
  int mt   = (idx >> 9) & 3;
  int wm   = (idx >> 11) & 3;
  int S    = idx >> 13;                     // 0..35
  int ph   = S >= 18;
  int j    = S - ph*18;
  int rs   = j >> 1;
  int ch2  = j & 1;
  int k = wm*64 + mt*16 + (lane & 15);
  int c = ph*64 + ch2*32 + (lane >> 4)*8 + e;
  F[idx] = f2bf(ft[(k*C_IN + c)*9 + rs]);
}

// ---------------- main implicit-GEMM conv ----------------
// block: 512 thr (8 waves, 4M x 2N), output tile = 256 K_out x (16h x 16w)
// wave = 64k x 128px (4 mt x 8 nt of 16x16x32 frags), acc = 128 AGPR
// smX: one 64-ch phase of 18x18 halo, [cell(324)][64] bf16 = 41,472 B
//   -> 2 blocks/CU (reg-bound at 4 waves/SIMD); restaged once at i=18.
// Barrier-free K-loop otherwise; A: fragment-packed F, global->reg depth-1 dbuf.
__global__ __launch_bounds__(512, 2) void conv_gemm(const unsigned short* __restrict__ xT,
                                                    const unsigned short* __restrict__ F,
                                                    float* __restrict__ out) {
  __shared__ unsigned short smX[324*64];      // 41,472 B
  // bijective XCD swizzle: 1568 blocks = 8 XCDs x 196
  const int bid  = blockIdx.y*49 + blockIdx.x;
  const int wgid = (bid & 7)*196 + (bid >> 3);
  const int tile = wgid % 49;                 // 7 h-tiles x 7 w-tiles
  const int n    = wgid / 49;
  const int tid  = threadIdx.x;
  const int lane = tid & 63;
  const int wid  = tid >> 6;
  const int wm   = wid & 3;                   // M quadrant (64 k each)
  const int wn   = wid >> 2;                  // N half (8 h-rows each)
  const int l15  = lane & 15;
  const int lhi  = lane >> 4;                 // 0..3
  const int th   = tile / 7;
  const int tw   = tile - th*7;
  const int h0   = th*16;
  const int w0   = tw*16;

  int browb[8];
  #pragma unroll
  for (int nt = 0; nt < 8; ++nt)
    browb[nt] = ((wn*8 + nt)*18 + l15)*64;    // halo cell * 64 shorts

  f32x4 acc[4][8];
  #pragma unroll
  for (int mt = 0; mt < 4; ++mt)
    #pragma unroll
    for (int nt = 0; nt < 8; ++nt)
      acc[mt][nt] = (f32x4){0.f, 0.f, 0.f, 0.f};

  const unsigned short* xbase = xT + (size_t)n*H_IN*W_IN*128;
  auto stage_halo = [&](int ph) {
    const unsigned short* xb = xbase + ph*64;
    #pragma unroll
    for (int k = 0; k < 6; ++k) {
      int ci = k*512 + tid;                   // < 2592 chunks of 16 B
      if (ci < 2592) {
        int cell = ci >> 3, sub = ci & 7;
        int hh = cell / 18, ww = cell - hh*18;
        int hc = h0 + hh; if (hc > 111) hc = 111;
        int wc = w0 + ww; if (wc > 111) wc = 111;
        gll16(xb + ((size_t)(hc*W_IN + wc))*128 + sub*8, &smX[ci*8]);
      }
    }
  };

  // per-wave A base; slice stride 8192 shorts
  const unsigned short* Aw = F + wm*2048 + lane*8;
  short8 aA[4], aB[4];
  #pragma unroll
  for (int u = 0; u < 4; ++u)
    aA[u] = *(const short8*)(Aw + u*512);

  stage_halo(0);
  __syncthreads();   // drains gll16 queue

#define COMPUTE(J, AREG)                                                         \
  {                                                                              \
    const int jj = (J) - ((J) >= 18 ? 18 : 0);                                   \
    const int rs = jj >> 1, ch2 = jj & 1;                                        \
    const int r = rs/3, s = rs - r*3;                                            \
    const int key  = ((l15 + s) & 7) << 3;                                       \
    const int off  = (r*18 + s)*64 + ((ch2*32 + lhi*8) ^ key);                   \
    __builtin_amdgcn_s_setprio(1);                                               \
    _Pragma("unroll")                                                            \
    for (int nt = 0; nt < 8; ++nt) {                                             \
      short8 b = *(const short8*)&smX[browb[nt] + off];                          \
      _Pragma("unroll")                                                          \
      for (int mt = 0; mt < 4; ++mt)                                             \
        acc[mt][nt] = __builtin_amdgcn_mfma_f32_16x16x32_bf16(AREG[mt], b, acc[mt][nt], 0, 0, 0); \
    }                                                                            \
    __builtin_amdgcn_s_setprio(0);                                               \
  }

  for (int i = 0; i < 36; i += 2) {
    if (i == 18) {
      __syncthreads();               // all waves done reading ph0
      stage_halo(1);
      __syncthreads();               // ph1 landed (syncthreads drains vmcnt)
    }
    {
      const unsigned short* As = Aw + (size_t)(i + 1)*8192;
      #pragma unroll
      for (int u = 0; u < 4; ++u)
        aB[u] = *(const short8*)(As + u*512);
    }
    COMPUTE(i, aA);
    if (i + 2 < 36) {
      const unsigned short* As = Aw + (size_t)(i + 2)*8192;
      #pragma unroll
      for (int u = 0; u < 4; ++u)
        aA[u] = *(const short8*)(As + u*512);
    }
    COMPUTE(i + 1, aB);
  }
#undef COMPUTE

  // epilogue: D frag: col(px)=l15, row(k)=lhi*4+reg
  const int wv = w0 + l15;
  #pragma unroll
  for (int nt = 0; nt < 8; ++nt) {
    int hv = h0 + wn*8 + nt;
    if (hv < H_OUTD && wv < W_OUTD) {
      float* po = out + (size_t)n*K_OUT*(H_OUTD*W_OUTD) + hv*W_OUTD + wv;
      #pragma unroll
      for (int mt = 0; mt < 4; ++mt) {
        #pragma unroll
        for (int reg = 0; reg < 4; ++reg) {
          int k = wm*64 + mt*16 + lhi*4 + reg;
          po[(size_t)k*(H_OUTD*W_OUTD)] = acc[mt][nt][reg];
        }
      }
    }
  }
}

// ---------------- fallback (ws too small): naive fp32 ----------------
__global__ void naive_conv(const float* __restrict__ x, const float* __restrict__ ft,
                           float* __restrict__ out) {
  int idx = blockIdx.x*256 + threadIdx.x;
  int total = NBATCH*K_OUT*H_OUTD*W_OUTD;
  if (idx >= total) return;
  int w = idx % W_OUTD; int t = idx / W_OUTD;
  int h = t % H_OUTD; t /= H_OUTD;
  int k = t % K_OUT; int nn = t / K_OUT;
  float acc = 0.f;
  for (int c = 0; c < C_IN; ++c)
    for (int r = 0; r < 3; ++r)
      for (int s = 0; s < 3; ++s)
        acc += x[((size_t)(nn*C_IN + c)*H_IN + h + r)*W_IN + w + s]
             * ft[((k*C_IN + c)*3 + r)*3 + s];
  out[idx] = acc;
}

extern "C" void kernel_launch(void* const* d_in, const int* in_sizes, int n_in,
                              void* d_out, int out_size, void* d_ws, size_t ws_size,
                              hipStream_t stream) {
  (void)in_sizes; (void)n_in; (void)out_size;
  const float* x  = (const float*)d_in[0];
  const float* ft = (const float*)d_in[1];
  float* out = (float*)d_out;
  size_t need = (size_t)(XT_ELEMS + F_ELEMS) * sizeof(unsigned short);
  if (ws_size >= need) {
    unsigned short* xT = (unsigned short*)d_ws;
    unsigned short* F  = xT + XT_ELEMS;
    xpose_kernel<<<dim3(112, 32), 256, 0, stream>>>(x, xT);
    fprep_kernel<<<dim3(1152), 256, 0, stream>>>(ft, F);
    conv_gemm<<<dim3(49, 32), 512, 0, stream>>>(xT, F, out);
  } else {
    int total = NBATCH*K_OUT*H_OUTD*W_OUTD;
    naive_conv<<<(total + 255)/256, 256, 0, stream>>>(x, ft, out);
  }
}